// Round 3
// baseline (370.875 us; speedup 1.0000x reference)
//
#include <hip/hip_runtime.h>

// Problem constants (from reference)
#define B_  16
#define T_  2048
#define IN_ 512
#define H_  512
#define M_  (B_ * T_)

// GEMM tiling — R5 structure, the measured local optimum (212us, VGPR 116).
// History: R6 (256,4) bound -> acc spill -> 3048us. R7 2-reg-set ping-pong
// -> VGPR 192 -> 298us. R8 persistent fusion -> occupancy coupling -> 529us.
// R9 1-barrier ping-pong -> mid-compute vmcnt drain -> 230us. KEEP THIS.
#define BM 128
#define BN 128
#define BK 16
#define LDT (BM + 4)

static __device__ __forceinline__ float4 ld4(const float* p) {
    return *reinterpret_cast<const float4*>(p);
}

// ---------------------------------------------------------------------------
// Kernel 1: h[m][n] = sum_k x[m][k]*W[n][k] + b[n], fp32 VALU.
// k accumulated strictly in order 0..511 with fmaf -> bit-matches np ref
// (absmax 0.0 across R2-R11). DO NOT reorder the k loop.
// Single LDS buffer + register prefetch of next k-tile (R5 body, verbatim).
// BYTE-IDENTICAL since the 370us round — do not touch this kernel.
// ---------------------------------------------------------------------------
__global__ __launch_bounds__(256)
void gemm_xwT(const float* __restrict__ X, const float* __restrict__ W,
              const float* __restrict__ bias, float* __restrict__ Hout) {
    __shared__ float As[BK][LDT];
    __shared__ float Bs[BK][LDT];

    const int tid = threadIdx.x;
    const int m0  = blockIdx.x * BM;   // 256 m-tiles
    const int n0  = blockIdx.y * BN;   // 4 n-tiles

    const int tx = tid & 15;           // col group
    const int ty = tid >> 4;           // row group

    const int row = tid >> 2;          // 0..63
    const int kph = (tid & 3) * 4;     // 0,4,8,12

    const float* pa0 = X + (size_t)(m0 + row) * IN_ + kph;
    const float* pa1 = pa0 + (size_t)64 * IN_;
    const float* pb0 = W + (size_t)(n0 + row) * IN_ + kph;
    const float* pb1 = pb0 + (size_t)64 * IN_;

    float4 ra0 = ld4(pa0), ra1 = ld4(pa1), rb0 = ld4(pb0), rb1 = ld4(pb1);

    float acc[8][8];
#pragma unroll
    for (int i = 0; i < 8; ++i)
#pragma unroll
        for (int j = 0; j < 8; ++j) acc[i][j] = 0.0f;

    for (int k0 = 0; k0 < IN_; k0 += BK) {
        As[kph + 0][row]      = ra0.x;  As[kph + 1][row]      = ra0.y;
        As[kph + 2][row]      = ra0.z;  As[kph + 3][row]      = ra0.w;
        As[kph + 0][row + 64] = ra1.x;  As[kph + 1][row + 64] = ra1.y;
        As[kph + 2][row + 64] = ra1.z;  As[kph + 3][row + 64] = ra1.w;
        Bs[kph + 0][row]      = rb0.x;  Bs[kph + 1][row]      = rb0.y;
        Bs[kph + 2][row]      = rb0.z;  Bs[kph + 3][row]      = rb0.w;
        Bs[kph + 0][row + 64] = rb1.x;  Bs[kph + 1][row + 64] = rb1.y;
        Bs[kph + 2][row + 64] = rb1.z;  Bs[kph + 3][row + 64] = rb1.w;
        __syncthreads();

        // prefetch next k-tile into registers; drains during the 16-k compute
        if (k0 + BK < IN_) {
            ra0 = ld4(pa0 + k0 + BK);  ra1 = ld4(pa1 + k0 + BK);
            rb0 = ld4(pb0 + k0 + BK);  rb1 = ld4(pb1 + k0 + BK);
        }

#pragma unroll
        for (int k = 0; k < BK; ++k) {
            float4 av0 = ld4(&As[k][ty * 4]);
            float4 av1 = ld4(&As[k][ty * 4 + 64]);
            float4 bv0 = ld4(&Bs[k][tx * 4]);
            float4 bv1 = ld4(&Bs[k][tx * 4 + 64]);
            const float am[8] = {av0.x, av0.y, av0.z, av0.w,
                                 av1.x, av1.y, av1.z, av1.w};
            const float bn8[8] = {bv0.x, bv0.y, bv0.z, bv0.w,
                                  bv1.x, bv1.y, bv1.z, bv1.w};
#pragma unroll
            for (int i = 0; i < 8; ++i)
#pragma unroll
                for (int j = 0; j < 8; ++j)
                    acc[i][j] = fmaf(am[i], bn8[j], acc[i][j]);
        }
        __syncthreads();
    }

    // epilogue: + bias (bias is zeros -> exact), coalesced float4 stores
    float4 bb0 = ld4(&bias[n0 + tx * 4]);
    float4 bb1 = ld4(&bias[n0 + tx * 4 + 64]);
#pragma unroll
    for (int i = 0; i < 8; ++i) {
        const int r = m0 + ((i < 4) ? (ty * 4 + i) : (64 + ty * 4 + (i - 4)));
        float4 o0, o1;
        o0.x = acc[i][0] + bb0.x;  o0.y = acc[i][1] + bb0.y;
        o0.z = acc[i][2] + bb0.z;  o0.w = acc[i][3] + bb0.w;
        o1.x = acc[i][4] + bb1.x;  o1.y = acc[i][5] + bb1.y;
        o1.z = acc[i][6] + bb1.z;  o1.w = acc[i][7] + bb1.w;
        *reinterpret_cast<float4*>(&Hout[(size_t)r * H_ + n0 + tx * 4])      = o0;
        *reinterpret_cast<float4*>(&Hout[(size_t)r * H_ + n0 + tx * 4 + 64]) = o1;
    }
}

// ---------------------------------------------------------------------------
// Kernel 2: GIF neuron scan. One thread per (b,h) chain; T=2048 steps.
// R12 POST-MORTEM of R10/R11: neither ALU-chain length (-2 ops: null) nor
// store-reg-hazard batching (null) moved the ~187 cy/step. Remaining model:
// fixed per-step cost of the vmem machinery itself (per-wave vmem op
// issue/queue overhead + 64-bit addr arithmetic on every strided scalar
// access), which neither experiment reduced in COUNT.
// R12: cut vmem instruction count 4x. The wave owns 64 consecutive h of one
// b, so 32 time-rows are 8x global_load_dwordx4 per lane; transpose through
// LDS (ds_write_b128 -> per-step ds_read_b32). Symmetrically, spikes are
// gathered per-step into LDS (ds_write_b32) and drained as 8x
// global_store_dwordx4. Single wave per workgroup -> DS ops are in-order ->
// NO barriers needed. All per-step addresses become LDS immediate offsets.
// Arithmetic statements byte-identical to R10/R11 (absmax 0.0). DO NOT touch.
// ---------------------------------------------------------------------------
#define SPF 32

__device__ __forceinline__
void scan_compute_lds(const float* __restrict__ buf, float* __restrict__ outcol,
                      float& v, float& theta) {
    const float DECAY_F = 0.9048374180359595f;  // exp(-1/10)
    const float ALPHA_F = 0.01f;
#pragma unroll
    for (int j = 0; j < SPF; ++j) {
        float cur = buf[j];
        v = v * DECAY_F + cur;
        float cl = 32.0f * theta;                  // L * theta * 2
        v = __builtin_amdgcn_fmed3f(v, -cl, cl);   // == fminf(fmaxf(v,-cl),cl)

        // ---- v/theta: raw rcp seed + Markstein correction (validated) ----
        float r0 = __builtin_amdgcn_rcpf(theta);   // ~1 ulp seed
        float q0 = v * r0;
        float er = fmaf(-theta, q0, v);            // exact residual
        float q  = fmaf(er, r0, q0);               // RN quotient to O(ulp^2)
        // ------------------------------------------------------------------

        float s = floorf(q);
        s = __builtin_amdgcn_fmed3f(s, 0.0f, 16.0f); // == fminf(fmaxf(s,0),16)
        v = v - s * theta;
        theta = theta + ALPHA_F * s - ALPHA_F * (theta - 1.0f);
        outcol[(size_t)j * 64] = s;                // LDS ds_write_b32, imm offs
    }
}

__global__ __launch_bounds__(64, 1)
void gif_scan(const float* __restrict__ Hbuf, float* __restrict__ spikes,
              float* __restrict__ vout, float* __restrict__ thout) {
    // one wave per workgroup; LDS private to the wave, DS in-order -> no syncs
    __shared__ float INA[SPF][64];
    __shared__ float INB[SPF][64];
    __shared__ float OUTS[SPF][64];

    const int lane = threadIdx.x;          // 0..63
    const int wg   = blockIdx.x;           // 0..127
    const int gid  = wg * 64 + lane;
    const int b    = gid >> 9;
    const int h0   = (wg * 64) & 511;      // wave's h base (64-aligned)
    const int lr   = lane >> 4;            // 0..3   row-in-quad
    const int lc   = (lane & 15) * 4;      // 0..60  col (float4)

    // vectorized global base: row lr, cols h0+lc .. +3 (256B/row per wave)
    const float* gin  = Hbuf   + (size_t)b * T_ * H_ + (size_t)lr * H_ + h0 + lc;
    float*       gout = spikes + (size_t)b * T_ * H_ + (size_t)lr * H_ + h0 + lc;

    float4 stage[8];
    float  bufR[SPF];

    // prologue: rows 0..31 -> INA
#pragma unroll
    for (int k = 0; k < 8; ++k) stage[k] = ld4(gin + (size_t)(4 * k) * H_);
#pragma unroll
    for (int k = 0; k < 8; ++k)
        *reinterpret_cast<float4*>(&INA[4 * k + lr][lc]) = stage[k];

    float v = 0.0f, theta = 1.0f;
    for (int t0 = 0; t0 < T_; t0 += 2 * SPF) {     // 32 iters, no tail
        // issue loads for batch t0+32 (land during compute of batch t0)
#pragma unroll
        for (int k = 0; k < 8; ++k)
            stage[k] = ld4(gin + (size_t)(t0 + SPF + 4 * k) * H_);

        // LDS -> regs (32x ds_read_b32, imm offsets), then pure-ALU 32 steps
#pragma unroll
        for (int j = 0; j < SPF; ++j) bufR[j] = INA[j][lane];
        scan_compute_lds(bufR, &OUTS[0][lane], v, theta);

        // drain spikes rows t0..t0+31 (transpose gather, 8x dwordx4 stores)
#pragma unroll
        for (int k = 0; k < 8; ++k) {
            float4 o = *reinterpret_cast<const float4*>(&OUTS[4 * k + lr][lc]);
            *reinterpret_cast<float4*>(gout + (size_t)(t0 + 4 * k) * H_) = o;
        }

        // commit staged batch t0+32 into INB (loads had full compute to land)
#pragma unroll
        for (int k = 0; k < 8; ++k)
            *reinterpret_cast<float4*>(&INB[4 * k + lr][lc]) = stage[k];

        // issue loads for batch t0+64
        if (t0 + 2 * SPF < T_) {
#pragma unroll
            for (int k = 0; k < 8; ++k)
                stage[k] = ld4(gin + (size_t)(t0 + 2 * SPF + 4 * k) * H_);
        }

#pragma unroll
        for (int j = 0; j < SPF; ++j) bufR[j] = INB[j][lane];
        scan_compute_lds(bufR, &OUTS[0][lane], v, theta);

#pragma unroll
        for (int k = 0; k < 8; ++k) {
            float4 o = *reinterpret_cast<const float4*>(&OUTS[4 * k + lr][lc]);
            *reinterpret_cast<float4*>(gout + (size_t)(t0 + SPF + 4 * k) * H_) = o;
        }

        if (t0 + 2 * SPF < T_) {
#pragma unroll
            for (int k = 0; k < 8; ++k)
                *reinterpret_cast<float4*>(&INA[4 * k + lr][lc]) = stage[k];
        }
    }
    vout[gid]  = v;
    thout[gid] = theta;
}

// ---------------------------------------------------------------------------
extern "C" void kernel_launch(void* const* d_in, const int* in_sizes, int n_in,
                              void* d_out, int out_size, void* d_ws, size_t ws_size,
                              hipStream_t stream) {
    const float* x    = (const float*)d_in[0];   // [16, 2048, 512]
    const float* W    = (const float*)d_in[1];   // [512, 512]
    const float* bias = (const float*)d_in[2];   // [512]

    float* out    = (float*)d_out;
    float* spikes = out;
    float* v_f    = out + (size_t)M_ * H_;
    float* th_f   = v_f + (size_t)B_ * H_;

    float* hbuf   = (float*)d_ws;                // 64 MiB scratch for h

    dim3 grid(M_ / BM, H_ / BN);                 // 256 x 4
    gemm_xwT<<<grid, 256, 0, stream>>>(x, W, bias, hbuf);
    gif_scan<<<(B_ * H_) / 64, 64, 0, stream>>>(hbuf, spikes, v_f, th_f);
}